// Round 8
// baseline (233.138 us; speedup 1.0000x reference)
//
#include <hip/hip_runtime.h>
#include <cstdint>
#include <cmath>

#define BB   2
#define NN   2048
#define DIMM 1024
#define NHH  16
#define DHH  64
#define MMR  (BB * NN)

typedef _Float16 half8  __attribute__((ext_vector_type(8)));
typedef _Float16 half4v __attribute__((ext_vector_type(4)));
typedef float    f32x4  __attribute__((ext_vector_type(4)));

#define GLD16(gp, lp)                                                          \
  __builtin_amdgcn_global_load_lds(                                            \
      (const __attribute__((address_space(1))) unsigned int*)(gp),             \
      (__attribute__((address_space(3))) unsigned int*)(lp), 16, 0, 0)

// ---------------- convert x (fp32 -> f16) ----------------
__global__ __launch_bounds__(256) void cvt_x_kernel(const float* __restrict__ x,
                                                    _Float16* __restrict__ xh) {
  int i = (blockIdx.x * 256 + threadIdx.x) * 4;
  float4 v = *(const float4*)(x + i);
  half4v h;
  h[0] = (_Float16)v.x; h[1] = (_Float16)v.y;
  h[2] = (_Float16)v.z; h[3] = (_Float16)v.w;
  *(half4v*)(xh + i) = h;
}

// ---------------- transpose + convert weights: W[k][n] -> Wt[n][k] f16 ----------------
__global__ __launch_bounds__(256) void transpose_w_kernel(
    const float* __restrict__ Wq, const float* __restrict__ Wk,
    const float* __restrict__ Wv, const float* __restrict__ Wo,
    _Float16* __restrict__ wt) {
  __shared__ float tile[64][65];
  int z = blockIdx.z;
  const float* W = (z == 0) ? Wq : (z == 1) ? Wk : (z == 2) ? Wv : Wo;
  _Float16* dst = wt + (size_t)z * 1024 * 1024;
  int r0 = blockIdx.x * 64;
  int c0 = blockIdx.y * 64;
  int t = threadIdx.x;
  int tr = t >> 4;
  int tc = (t & 15) * 4;
#pragma unroll
  for (int i = 0; i < 4; ++i) {
    float4 v = *(const float4*)(W + (size_t)(r0 + tr + i * 16) * 1024 + c0 + tc);
    tile[tr + i * 16][tc + 0] = v.x;
    tile[tr + i * 16][tc + 1] = v.y;
    tile[tr + i * 16][tc + 2] = v.z;
    tile[tr + i * 16][tc + 3] = v.w;
  }
  __syncthreads();
#pragma unroll
  for (int i = 0; i < 4; ++i) {
    int nl = tr + i * 16;
    half4v hv;
    hv[0] = (_Float16)tile[tc + 0][nl];
    hv[1] = (_Float16)tile[tc + 1][nl];
    hv[2] = (_Float16)tile[tc + 2][nl];
    hv[3] = (_Float16)tile[tc + 3][nl];
    *(half4v*)(dst + (size_t)(c0 + nl) * 1024 + r0 + tc) = hv;
  }
}

// ---------------- QKV GEMM: 128x128 tile, BK=32, 2-deep, 32KB LDS ----------------
// R5's 64^2 was measured at 92% of its LDS-bandwidth roofline (56KB/iter per
// 32 MFMA). 128^2 halves bytes/MFMA (48KB/iter per 64 MFMA); BK=32 keeps LDS
// at 2x16KB=32KB so residency stays ~3-4 blocks/CU (R6's 64KB killed it).
// Loop = R5's exact 2-deep discipline: XOR buffer index (compile-time LDS
// bases -- R7's modulo-3 cur cost +8us of address VALU), stage next, vmcnt(4),
// barrier, 8 ds_read + 16 MFMA/wave, lgkmcnt(0), barrier.
// LDS layout (BK=32): row = 64B = 4 chunks of 16B; chunk slot = (k>>3) ^
// ((row>>1)&3). Each consecutive-8-lane group of a frag ds_read_b128 covers
// all 32 banks (2 lanes/bank over the full wave = free).
__global__ __launch_bounds__(256) void gemm_qkv_kernel(
    const _Float16* __restrict__ xh, const _Float16* __restrict__ wt,
    float* __restrict__ ko, float* __restrict__ vo,
    _Float16* __restrict__ qh, _Float16* __restrict__ kh,
    _Float16* __restrict__ vth) {
  __shared__ __align__(16) char smem[33280];
  _Float16* As = (_Float16*)smem;            // [2][4096] halfs, 16KB
  _Float16* Bs = (_Float16*)(smem + 16384);  // [2][4096] halfs, 16KB
  float (*Cs)[65] = (float(*)[65])smem;      // 128x65 f32 epilogue reuse (33.3KB)

  const int m0  = blockIdx.x * 128;
  const int ngl = (int)blockIdx.y * 128;
  const int mat = ngl >> 10;
  const int n0  = ngl & 1023;
  const _Float16* wb = wt + (size_t)mat * 1024 * 1024;
  const int t = threadIdx.x;
  const int wv = t >> 6, lane = t & 63, l16 = lane & 15, quad = lane >> 4;
  const int wr = wv >> 1, wc = wv & 1;
  // staging: wave wv covers rows wv*32..wv*32+31 (two passes of 16 rows).
  // lane -> row wv*32 + (lane>>2), slot lane&3 holds global chunk slot^((row>>1)&3)
  const int srow = wv * 32 + (lane >> 2);
  const int sg   = ((lane & 3) ^ ((lane >> 3) & 3)) * 8;   // (row>>1)&3 == (lane>>3)&3
  const _Float16* pa0 = xh + (size_t)(m0 + srow) * 1024 + sg;
  const _Float16* pb0 = wb + (size_t)(n0 + srow) * 1024 + sg;
  f32x4 acc[4][4] = {};
  const int ksl = (quad ^ ((l16 >> 1) & 3)) * 8;   // swizzled k-chunk slot (halfs)
  int aoff[4], boff[4];
#pragma unroll
  for (int mi = 0; mi < 4; ++mi) {
    int arow = wr * 64 + mi * 16 + l16;
    aoff[mi] = arow * 32 + ksl;    // arow*64B + slot*16B, in halfs
  }
#pragma unroll
  for (int nt = 0; nt < 4; ++nt) {
    int brow = wc * 64 + nt * 16 + l16;
    boff[nt] = brow * 32 + ksl;
  }

#define STAGE_AB(k0s, nb) do {                                                 \
    GLD16(pa0 + (k0s), As + (nb) * 4096 + wv * 1024);                          \
    GLD16(pa0 + 16384 + (k0s), As + (nb) * 4096 + wv * 1024 + 512);            \
    GLD16(pb0 + (k0s), Bs + (nb) * 4096 + wv * 1024);                          \
    GLD16(pb0 + 16384 + (k0s), Bs + (nb) * 4096 + wv * 1024 + 512);            \
  } while (0)

  STAGE_AB(0, 0);
  int cur = 0;
  for (int k0 = 0; k0 < 1024; k0 += 32) {
    if (k0 + 32 < 1024) {
      STAGE_AB(k0 + 32, cur ^ 1);
      asm volatile("s_waitcnt vmcnt(4)" ::: "memory");   // current tile landed
    } else {
      asm volatile("s_waitcnt vmcnt(0)" ::: "memory");
    }
    __builtin_amdgcn_s_barrier();
    asm volatile("" ::: "memory");
    const _Float16* Ab = As + cur * 4096;
    const _Float16* Bb = Bs + cur * 4096;
    half8 af[4], bf[4];
#pragma unroll
    for (int mi = 0; mi < 4; ++mi) af[mi] = *(const half8*)(Ab + aoff[mi]);
#pragma unroll
    for (int nt = 0; nt < 4; ++nt) bf[nt] = *(const half8*)(Bb + boff[nt]);
#pragma unroll
    for (int mi = 0; mi < 4; ++mi)
#pragma unroll
      for (int nt = 0; nt < 4; ++nt)
        acc[mi][nt] = __builtin_amdgcn_mfma_f32_16x16x32_f16(af[mi], bf[nt], acc[mi][nt], 0, 0, 0);
    // reads of buf[cur] must RETIRE before crossing: next iter's prefetch
    // overwrites this buffer (raw s_barrier does not drain lgkm).
    asm volatile("s_waitcnt lgkmcnt(0)" ::: "memory");
    __builtin_amdgcn_s_barrier();
    asm volatile("" ::: "memory");
    cur ^= 1;
  }
#undef STAGE_AB
  // ---------- epilogue (R6-validated): 2 rounds over column halves ----------
  const int lr = t >> 1;           // 0..127 (tile row)
  const int cseg = (t & 1) * 32;   // 0 or 32 within the 64-col head
  const int m = m0 + lr;
  const int b = m >> 11;
  const int pos = m & 2047;
  const float fpos = (float)pos;
  for (int ch = 0; ch < 2; ++ch) {
    __syncthreads();
    if (wc == ch) {
#pragma unroll
      for (int mi = 0; mi < 4; ++mi)
#pragma unroll
        for (int nt = 0; nt < 4; ++nt)
#pragma unroll
          for (int rr = 0; rr < 4; ++rr)
            Cs[wr * 64 + mi * 16 + quad * 4 + rr][nt * 16 + l16] = acc[mi][nt][rr];
    }
    __syncthreads();
    const int h = (n0 >> 6) + ch;
    const int bhh = b * NHH + h;
    float vals[32];
    if (mat == 2) {
#pragma unroll
      for (int j = 0; j < 32; ++j) vals[j] = Cs[lr][cseg + j];
    } else {
      const bool lo = (cseg == 0);
#pragma unroll
      for (int j = 0; j < 32; ++j) {
        float invf = exp2f((float)j * -0.41524101186092029f);
        float ang = fpos * invf;
        float sv, cv;
        sincosf(ang, &sv, &cv);
        float partner = lo ? -Cs[lr][2 * j + 1] : Cs[lr][2 * j];
        vals[j] = Cs[lr][cseg + j] * cv + partner * sv;
      }
    }
    size_t rowb = ((size_t)bhh * NN + pos) * DHH + cseg;
    if (mat == 0) {
#pragma unroll
      for (int j8 = 0; j8 < 4; ++j8) {
        half8 hv;
#pragma unroll
        for (int j = 0; j < 8; ++j) hv[j] = (_Float16)(vals[j8 * 8 + j] * 0.125f);
        *(half8*)(qh + rowb + j8 * 8) = hv;
      }
    } else if (mat == 1) {
#pragma unroll
      for (int j4 = 0; j4 < 8; ++j4) {
        float4 o;
        o.x = vals[j4 * 4 + 0]; o.y = vals[j4 * 4 + 1];
        o.z = vals[j4 * 4 + 2]; o.w = vals[j4 * 4 + 3];
        *(float4*)(ko + rowb + j4 * 4) = o;
      }
#pragma unroll
      for (int j8 = 0; j8 < 4; ++j8) {
        half8 hv;
#pragma unroll
        for (int j = 0; j < 8; ++j) hv[j] = (_Float16)vals[j8 * 8 + j];
        *(half8*)(kh + rowb + j8 * 8) = hv;
      }
    } else {
#pragma unroll
      for (int j4 = 0; j4 < 8; ++j4) {
        float4 o;
        o.x = vals[j4 * 4 + 0]; o.y = vals[j4 * 4 + 1];
        o.z = vals[j4 * 4 + 2]; o.w = vals[j4 * 4 + 3];
        *(float4*)(vo + rowb + j4 * 4) = o;
      }
#pragma unroll
      for (int j = 0; j < 32; ++j)
        vth[((size_t)bhh * DHH + cseg + j) * NN + pos] = (_Float16)vals[j];
    }
  }
}

// ---------------- MFMA flash attention v6 (causal), f16 ----------------
// 8 waves x 512 threads; uniform pair-blocks; XCD-chunked bh; 3-deep K/V
// pipeline with counted vmcnt. (R7, unchanged -- it gained ~20us.)
__global__ __launch_bounds__(512) void fattn_kernel(
    const _Float16* __restrict__ qh, const _Float16* __restrict__ kh,
    const _Float16* __restrict__ vth, _Float16* __restrict__ ah) {
  __shared__ __align__(16) _Float16 Kt[3][4096];
  __shared__ __align__(16) _Float16 Vt[3][4096];
  __shared__ __align__(16) _Float16 Pb[8][16][72];
  const int lin  = (int)blockIdx.x;          // 0..255
  const int xcd  = lin & 7;
  const int slot = lin >> 3;                 // 0..31 within XCD
  const int bh   = xcd * 4 + (slot & 3);     // 4 bh per XCD
  const int pair = slot >> 2;                // 0..7
  const int t = threadIdx.x;
  const int wv = t >> 6, lane = t & 63, l16 = lane & 15, quad = lane >> 4;
  const int b = bh >> 4, h = bh & 15;
  const _Float16* kg = kh + (size_t)bh * NN * DHH;
  const _Float16* vg = vth + (size_t)bh * DHH * NN;
  const int srow = t >> 3;
  const int sc   = ((t & 7) ^ (srow & 7)) * 8;
  half8 ones;
#pragma unroll
  for (int j = 0; j < 8; ++j) ones[j] = (_Float16)1.f;

#define STAGE_KV(tile, nb) do {                                                \
    const _Float16* kn_ = kg + (size_t)(tile) * 64 * DHH;                      \
    const _Float16* vn_ = vg + (tile) * 64;                                    \
    GLD16(kn_ + (size_t)srow * DHH + sc, &Kt[nb][0] + (wv * 64) * 8);          \
    GLD16(vn_ + (size_t)srow * NN + sc, &Vt[nb][0] + (wv * 64) * 8);           \
  } while (0)

  for (int job = 0; job < 2; ++job) {
    const int qb = (job == 0) ? (15 - pair) : pair;
    const int q0 = qb * 128;
    const int base = q0 + wv * 16;
    half8 qf0, qf1;
    {
      const _Float16* qp =
          qh + ((size_t)bh * NN + base + l16) * DHH + quad * 8;
      qf0 = *(const half8*)qp;
      qf1 = *(const half8*)(qp + 32);
    }
    f32x4 o[4] = {};
    f32x4 ls = {};
    const int ktmax = 2 * qb + 1;   // >= 1 always
    STAGE_KV(0, 0);
    STAGE_KV(1, 1);
    int cur = 0;
    for (int kt = 0; kt <= ktmax; ++kt) {
      if (kt + 2 <= ktmax) {
        int nb = cur + 2; if (nb >= 3) nb -= 3;
        STAGE_KV(kt + 2, nb);
        asm volatile("s_waitcnt vmcnt(4)" ::: "memory");  // tile kt landed
      } else if (kt + 1 <= ktmax) {
        asm volatile("s_waitcnt vmcnt(2)" ::: "memory");
      } else {
        asm volatile("s_waitcnt vmcnt(0)" ::: "memory");
      }
      __builtin_amdgcn_s_barrier();
      asm volatile("" ::: "memory");
      if (kt * 64 <= base + 15) {
        half8 kf[4][2], vf[4][2];
        const _Float16* Kb = &Kt[cur][0];
        const _Float16* Vb = &Vt[cur][0];
#pragma unroll
        for (int nt = 0; nt < 4; ++nt) {
          int row = nt * 16 + l16;
          int r7 = row & 7;
          kf[nt][0] = *(const half8*)(Kb + row * 64 + ((quad ^ r7) * 8));
          kf[nt][1] = *(const half8*)(Kb + row * 64 + (((quad + 4) ^ r7) * 8));
          vf[nt][0] = *(const half8*)(Vb + row * 64 + ((quad ^ r7) * 8));
          vf[nt][1] = *(const half8*)(Vb + row * 64 + (((quad + 4) ^ r7) * 8));
        }
        f32x4 s4[4];
#pragma unroll
        for (int nt = 0; nt < 4; ++nt) {
          f32x4 z = {};
          z = __builtin_amdgcn_mfma_f32_16x16x32_f16(qf0, kf[nt][0], z, 0, 0, 0);
          s4[nt] = __builtin_amdgcn_mfma_f32_16x16x32_f16(qf1, kf[nt][1], z, 0, 0, 0);
        }
        if (kt * 64 + 63 > base) {
#pragma unroll
          for (int nt = 0; nt < 4; ++nt) {
            int key = kt * 64 + nt * 16 + l16;
#pragma unroll
            for (int r = 0; r < 4; ++r) {
              float p = (key > base + quad * 4 + r) ? 0.f : __expf(s4[nt][r]);
              Pb[wv][quad * 4 + r][nt * 16 + l16] = (_Float16)p;
            }
          }
        } else {
#pragma unroll
          for (int nt = 0; nt < 4; ++nt)
#pragma unroll
            for (int r = 0; r < 4; ++r)
              Pb[wv][quad * 4 + r][nt * 16 + l16] = (_Float16)__expf(s4[nt][r]);
        }
        asm volatile("s_waitcnt lgkmcnt(0)" ::: "memory");
        half8 pf0 = *(const half8*)&Pb[wv][l16][quad * 8];
        half8 pf1 = *(const half8*)&Pb[wv][l16][32 + quad * 8];
#pragma unroll
        for (int nt = 0; nt < 4; ++nt) {
          o[nt] = __builtin_amdgcn_mfma_f32_16x16x32_f16(pf0, vf[nt][0], o[nt], 0, 0, 0);
          o[nt] = __builtin_amdgcn_mfma_f32_16x16x32_f16(pf1, vf[nt][1], o[nt], 0, 0, 0);
        }
        ls = __builtin_amdgcn_mfma_f32_16x16x32_f16(pf0, ones, ls, 0, 0, 0);
        ls = __builtin_amdgcn_mfma_f32_16x16x32_f16(pf1, ones, ls, 0, 0, 0);
      }
      asm volatile("s_waitcnt lgkmcnt(0)" ::: "memory");
      __builtin_amdgcn_s_barrier();
      asm volatile("" ::: "memory");
      cur = (cur == 2) ? 0 : cur + 1;
    }
#pragma unroll
    for (int r = 0; r < 4; ++r) {
      float inv = 1.f / ls[r];
      int pos = base + quad * 4 + r;
      size_t ob = ((size_t)(b * NN + pos)) * DIMM + h * DHH;
#pragma unroll
      for (int nt = 0; nt < 4; ++nt)
        ah[ob + nt * 16 + l16] = (_Float16)(o[nt][r] * inv);
    }
  }
#undef STAGE_KV
}

// ---------------- out GEMM: 64x64 tile, BK=64, 2-deep (R5 exact) + bias ----------------
__global__ __launch_bounds__(256) void gemm_out_kernel(
    const _Float16* __restrict__ ah, const _Float16* __restrict__ wot,
    const float* __restrict__ bo, float* __restrict__ out) {
  __shared__ __align__(16) char smem[32768];
  _Float16* As = (_Float16*)smem;
  _Float16* Bs = (_Float16*)(smem + 16384);
  const int m0 = blockIdx.x * 64;
  const int n0 = blockIdx.y * 64;
  const int t = threadIdx.x;
  const int wv = t >> 6, lane = t & 63, l16 = lane & 15, quad = lane >> 4;
  const int r  = t >> 3;
  const int cl = t & 7;
  const int csw = (cl ^ (r & 7)) * 8;
  const _Float16* pa0 = ah + (size_t)(m0 + r) * 1024 + csw;
  const _Float16* pa1 = pa0 + 32 * 1024;
  const _Float16* pb0 = wot + (size_t)(n0 + r) * 1024 + csw;
  const _Float16* pb1 = pb0 + 32 * 1024;
  f32x4 acc[4] = {};
  const int arow = wv * 16 + l16;
  const int a7 = arow & 7;
  GLD16(pa0, As + wv * 512);
  GLD16(pa1, As + 2048 + wv * 512);
  GLD16(pb0, Bs + wv * 512);
  GLD16(pb1, Bs + 2048 + wv * 512);
  int cur = 0;
  for (int k0 = 0; k0 < 1024; k0 += 64) {
    if (k0 + 64 < 1024) {
      const int nb = cur ^ 1;
      GLD16(pa0 + k0 + 64, As + nb * 4096 + wv * 512);
      GLD16(pa1 + k0 + 64, As + nb * 4096 + 2048 + wv * 512);
      GLD16(pb0 + k0 + 64, Bs + nb * 4096 + wv * 512);
      GLD16(pb1 + k0 + 64, Bs + nb * 4096 + 2048 + wv * 512);
      asm volatile("s_waitcnt vmcnt(4)" ::: "memory");
    } else {
      asm volatile("s_waitcnt vmcnt(0)" ::: "memory");
    }
    __builtin_amdgcn_s_barrier();
    asm volatile("" ::: "memory");
    const _Float16* Ab = As + cur * 4096;
    const _Float16* Bb = Bs + cur * 4096;
    half8 af0 = *(const half8*)(Ab + arow * 64 + (quad ^ a7) * 8);
    half8 af1 = *(const half8*)(Ab + arow * 64 + ((4 + quad) ^ a7) * 8);
#pragma unroll
    for (int nt = 0; nt < 4; ++nt) {
      int brow = nt * 16 + l16;
      int b7 = brow & 7;
      half8 bf0 = *(const half8*)(Bb + brow * 64 + (quad ^ b7) * 8);
      half8 bf1 = *(const half8*)(Bb + brow * 64 + ((4 + quad) ^ b7) * 8);
      acc[nt] = __builtin_amdgcn_mfma_f32_16x16x32_f16(af0, bf0, acc[nt], 0, 0, 0);
      acc[nt] = __builtin_amdgcn_mfma_f32_16x16x32_f16(af1, bf1, acc[nt], 0, 0, 0);
    }
    asm volatile("s_waitcnt lgkmcnt(0)" ::: "memory");
    __builtin_amdgcn_s_barrier();
    asm volatile("" ::: "memory");
    cur ^= 1;
  }
#pragma unroll
  for (int nt = 0; nt < 4; ++nt) {
    int col = n0 + nt * 16 + l16;
    float bias = bo[col];
#pragma unroll
    for (int rr = 0; rr < 4; ++rr) {
      out[(size_t)(m0 + wv * 16 + quad * 4 + rr) * 1024 + col] = acc[nt][rr] + bias;
    }
  }
}

extern "C" void kernel_launch(void* const* d_in, const int* in_sizes, int n_in,
                              void* d_out, int out_size, void* d_ws, size_t ws_size,
                              hipStream_t stream) {
  (void)in_sizes; (void)n_in; (void)out_size; (void)ws_size;
  const float* x  = (const float*)d_in[0];
  const float* Wq = (const float*)d_in[1];
  const float* Wk = (const float*)d_in[2];
  const float* Wv = (const float*)d_in[3];
  const float* Wo = (const float*)d_in[4];
  const float* bo = (const float*)d_in[5];

  float* out = (float*)d_out;
  float* ko  = out + (size_t)MMR * DIMM;
  float* vo  = ko + (size_t)BB * NHH * NN * DHH;

  char* w = (char*)d_ws;
  _Float16* xh  = (_Float16*)w;                   // 8 MB (dead after gemm_qkv)
  _Float16* ah  = (_Float16*)w;                   // 8 MB (reuses xh region)
  _Float16* wt  = (_Float16*)(w + (8u << 20));    // 8 MB
  _Float16* qh  = (_Float16*)(w + (16u << 20));   // 8 MB (b,h,n,dh) roped, *0.125
  _Float16* kh  = (_Float16*)(w + (24u << 20));   // 8 MB (b,h,n,dh) roped
  _Float16* vth = (_Float16*)(w + (32u << 20));   // 8 MB (b,h,dh,n)

  hipLaunchKernelGGL(cvt_x_kernel, dim3(4096), dim3(256), 0, stream, x, xh);
  hipLaunchKernelGGL(transpose_w_kernel, dim3(16, 16, 4), dim3(256), 0, stream,
                     Wq, Wk, Wv, Wo, wt);
  hipLaunchKernelGGL(gemm_qkv_kernel, dim3(32, 24), dim3(256), 0, stream,
                     xh, wt, ko, vo, qh, kh, vth);
  hipLaunchKernelGGL(fattn_kernel, dim3(256), dim3(512), 0, stream,
                     qh, kh, vth, ah);
  hipLaunchKernelGGL(gemm_out_kernel, dim3(64, 16), dim3(256), 0, stream,
                     ah, wt + (size_t)3 * 1024 * 1024, bo, out);
}

// Round 9
// 200.205 us; speedup vs baseline: 1.1645x; 1.1645x over previous
//
#include <hip/hip_runtime.h>
#include <cstdint>
#include <cmath>

#define BB   2
#define NN   2048
#define DIMM 1024
#define NHH  16
#define DHH  64
#define MMR  (BB * NN)

typedef _Float16 half8  __attribute__((ext_vector_type(8)));
typedef _Float16 half4v __attribute__((ext_vector_type(4)));
typedef float    f32x4  __attribute__((ext_vector_type(4)));

#define GLD16(gp, lp)                                                          \
  __builtin_amdgcn_global_load_lds(                                            \
      (const __attribute__((address_space(1))) unsigned int*)(gp),             \
      (__attribute__((address_space(3))) unsigned int*)(lp), 16, 0, 0)

// ---------------- convert x (fp32 -> f16) ----------------
__global__ __launch_bounds__(256) void cvt_x_kernel(const float* __restrict__ x,
                                                    _Float16* __restrict__ xh) {
  int i = (blockIdx.x * 256 + threadIdx.x) * 4;
  float4 v = *(const float4*)(x + i);
  half4v h;
  h[0] = (_Float16)v.x; h[1] = (_Float16)v.y;
  h[2] = (_Float16)v.z; h[3] = (_Float16)v.w;
  *(half4v*)(xh + i) = h;
}

// ---------------- transpose + convert weights: W[k][n] -> Wt[n][k] f16 ----------------
__global__ __launch_bounds__(256) void transpose_w_kernel(
    const float* __restrict__ Wq, const float* __restrict__ Wk,
    const float* __restrict__ Wv, const float* __restrict__ Wo,
    _Float16* __restrict__ wt) {
  __shared__ float tile[64][65];
  int z = blockIdx.z;
  const float* W = (z == 0) ? Wq : (z == 1) ? Wk : (z == 2) ? Wv : Wo;
  _Float16* dst = wt + (size_t)z * 1024 * 1024;
  int r0 = blockIdx.x * 64;
  int c0 = blockIdx.y * 64;
  int t = threadIdx.x;
  int tr = t >> 4;
  int tc = (t & 15) * 4;
#pragma unroll
  for (int i = 0; i < 4; ++i) {
    float4 v = *(const float4*)(W + (size_t)(r0 + tr + i * 16) * 1024 + c0 + tc);
    tile[tr + i * 16][tc + 0] = v.x;
    tile[tr + i * 16][tc + 1] = v.y;
    tile[tr + i * 16][tc + 2] = v.z;
    tile[tr + i * 16][tc + 3] = v.w;
  }
  __syncthreads();
#pragma unroll
  for (int i = 0; i < 4; ++i) {
    int nl = tr + i * 16;
    half4v hv;
    hv[0] = (_Float16)tile[tc + 0][nl];
    hv[1] = (_Float16)tile[tc + 1][nl];
    hv[2] = (_Float16)tile[tc + 2][nl];
    hv[3] = (_Float16)tile[tc + 3][nl];
    *(half4v*)(dst + (size_t)(c0 + nl) * 1024 + r0 + tc) = hv;
  }
}

// ---------------- QKV GEMM: 64x64 tile, BK=64, dbuf + counted vmcnt ----------------
// R5-measured best (57us, 450 TF). Session evidence: every lower-grid config
// (128^2 BK64/BK32, 3-deep) regressed -- at K=1024 the per-iter 16KB stage
// (~300cy L2 delivery) is hidden only by 12-queued-blocks/CU TLP, which
// 64^2 x 3072 blocks uniquely provides. Do not reduce grid.
__global__ __launch_bounds__(256) void gemm_qkv_kernel(
    const _Float16* __restrict__ xh, const _Float16* __restrict__ wt,
    float* __restrict__ ko, float* __restrict__ vo,
    _Float16* __restrict__ qh, _Float16* __restrict__ kh,
    _Float16* __restrict__ vth) {
  __shared__ __align__(16) char smem[32768];
  _Float16* As = (_Float16*)smem;            // [2][64][64] halfs, 16KB
  _Float16* Bs = (_Float16*)(smem + 16384);  // [2][64][64] halfs, 16KB
  float (*Cs)[65] = (float(*)[65])smem;      // 64x65 f32 epilogue reuse (16.6KB)

  const int m0  = blockIdx.x * 64;
  const int ngl = blockIdx.y * 64;
  const int mat = ngl >> 10;
  const int n0  = ngl & 1023;
  const _Float16* wb = wt + (size_t)mat * 1024 * 1024;
  const int t = threadIdx.x;
  const int wv = t >> 6, lane = t & 63, l16 = lane & 15, quad = lane >> 4;
  const int r  = t >> 3;       // 0..31
  const int cl = t & 7;
  const int csw = (cl ^ (r & 7)) * 8;   // (r+32)&7 == r&7
  const _Float16* pa0 = xh + (size_t)(m0 + r) * 1024 + csw;
  const _Float16* pa1 = pa0 + 32 * 1024;
  const _Float16* pb0 = wb + (size_t)(n0 + r) * 1024 + csw;
  const _Float16* pb1 = pb0 + 32 * 1024;
  f32x4 acc[4] = {};
  const int arow = wv * 16 + l16;
  const int a7 = arow & 7;
  GLD16(pa0, As + wv * 512);
  GLD16(pa1, As + 2048 + wv * 512);
  GLD16(pb0, Bs + wv * 512);
  GLD16(pb1, Bs + 2048 + wv * 512);
  int cur = 0;
  for (int k0 = 0; k0 < 1024; k0 += 64) {
    if (k0 + 64 < 1024) {
      const int nb = cur ^ 1;
      GLD16(pa0 + k0 + 64, As + nb * 4096 + wv * 512);
      GLD16(pa1 + k0 + 64, As + nb * 4096 + 2048 + wv * 512);
      GLD16(pb0 + k0 + 64, Bs + nb * 4096 + wv * 512);
      GLD16(pb1 + k0 + 64, Bs + nb * 4096 + 2048 + wv * 512);
      asm volatile("s_waitcnt vmcnt(4)" ::: "memory");
    } else {
      asm volatile("s_waitcnt vmcnt(0)" ::: "memory");
    }
    __builtin_amdgcn_s_barrier();
    asm volatile("" ::: "memory");
    const _Float16* Ab = As + cur * 4096;
    const _Float16* Bb = Bs + cur * 4096;
    half8 af0 = *(const half8*)(Ab + arow * 64 + (quad ^ a7) * 8);
    half8 af1 = *(const half8*)(Ab + arow * 64 + ((4 + quad) ^ a7) * 8);
#pragma unroll
    for (int nt = 0; nt < 4; ++nt) {
      int brow = nt * 16 + l16;
      int b7 = brow & 7;
      half8 bf0 = *(const half8*)(Bb + brow * 64 + (quad ^ b7) * 8);
      half8 bf1 = *(const half8*)(Bb + brow * 64 + ((4 + quad) ^ b7) * 8);
      acc[nt] = __builtin_amdgcn_mfma_f32_16x16x32_f16(af0, bf0, acc[nt], 0, 0, 0);
      acc[nt] = __builtin_amdgcn_mfma_f32_16x16x32_f16(af1, bf1, acc[nt], 0, 0, 0);
    }
    asm volatile("s_waitcnt lgkmcnt(0)" ::: "memory");
    __builtin_amdgcn_s_barrier();
    asm volatile("" ::: "memory");
    cur ^= 1;
  }
  // ---------- epilogue: RoPE/scatter through Cs ----------
#pragma unroll
  for (int nt = 0; nt < 4; ++nt)
#pragma unroll
    for (int rr = 0; rr < 4; ++rr)
      Cs[wv * 16 + quad * 4 + rr][nt * 16 + l16] = acc[nt][rr];
  __syncthreads();
  int lr = t >> 2;
  int cseg = (t & 3) * 16;
  int m = m0 + lr;
  int b = m >> 11;
  int pos = m & 2047;
  int h = n0 >> 6;
  int bhh = b * NHH + h;
  float vals[16];
  if (mat == 2) {
#pragma unroll
    for (int j = 0; j < 16; ++j) vals[j] = Cs[lr][cseg + j];
  } else {
    float fpos = (float)pos;
#pragma unroll
    for (int j = 0; j < 16; ++j) {
      int i = cseg + j;
      int jd = (i < 32) ? i : (i - 32);
      float invf = exp2f((float)jd * -0.41524101186092029f);
      float ang = fpos * invf;
      float sv, cv;
      sincosf(ang, &sv, &cv);
      float partner = (i < 32) ? -Cs[lr][2 * i + 1] : Cs[lr][2 * (i - 32)];
      vals[j] = Cs[lr][i] * cv + partner * sv;
    }
  }
  size_t rowb = ((size_t)bhh * NN + pos) * DHH + cseg;
  if (mat == 0) {
    half8 h0, h1;
#pragma unroll
    for (int j = 0; j < 8; ++j) { h0[j] = (_Float16)(vals[j] * 0.125f); h1[j] = (_Float16)(vals[8 + j] * 0.125f); }
    *(half8*)(qh + rowb) = h0;
    *(half8*)(qh + rowb + 8) = h1;
  } else if (mat == 1) {
#pragma unroll
    for (int j4 = 0; j4 < 4; ++j4) {
      float4 o;
      o.x = vals[j4 * 4 + 0]; o.y = vals[j4 * 4 + 1];
      o.z = vals[j4 * 4 + 2]; o.w = vals[j4 * 4 + 3];
      *(float4*)(ko + rowb + j4 * 4) = o;
    }
    half8 h0, h1;
#pragma unroll
    for (int j = 0; j < 8; ++j) { h0[j] = (_Float16)vals[j]; h1[j] = (_Float16)vals[8 + j]; }
    *(half8*)(kh + rowb) = h0;
    *(half8*)(kh + rowb + 8) = h1;
  } else {
#pragma unroll
    for (int j4 = 0; j4 < 4; ++j4) {
      float4 o;
      o.x = vals[j4 * 4 + 0]; o.y = vals[j4 * 4 + 1];
      o.z = vals[j4 * 4 + 2]; o.w = vals[j4 * 4 + 3];
      *(float4*)(vo + rowb + j4 * 4) = o;
    }
#pragma unroll
    for (int j = 0; j < 16; ++j)
      vth[((size_t)bhh * DHH + cseg + j) * NN + pos] = (_Float16)vals[j];
  }
}

// ---------------- MFMA flash attention v6 (causal), f16 ----------------
// 8 waves x 512 threads; uniform pair-blocks; XCD-chunked bh; 3-deep K/V
// pipeline with counted vmcnt. (R7-measured: ~18us faster than v5.)
__global__ __launch_bounds__(512) void fattn_kernel(
    const _Float16* __restrict__ qh, const _Float16* __restrict__ kh,
    const _Float16* __restrict__ vth, _Float16* __restrict__ ah) {
  __shared__ __align__(16) _Float16 Kt[3][4096];
  __shared__ __align__(16) _Float16 Vt[3][4096];
  __shared__ __align__(16) _Float16 Pb[8][16][72];
  const int lin  = (int)blockIdx.x;          // 0..255
  const int xcd  = lin & 7;
  const int slot = lin >> 3;                 // 0..31 within XCD
  const int bh   = xcd * 4 + (slot & 3);     // 4 bh per XCD
  const int pair = slot >> 2;                // 0..7
  const int t = threadIdx.x;
  const int wv = t >> 6, lane = t & 63, l16 = lane & 15, quad = lane >> 4;
  const int b = bh >> 4, h = bh & 15;
  const _Float16* kg = kh + (size_t)bh * NN * DHH;
  const _Float16* vg = vth + (size_t)bh * DHH * NN;
  const int srow = t >> 3;
  const int sc   = ((t & 7) ^ (srow & 7)) * 8;
  half8 ones;
#pragma unroll
  for (int j = 0; j < 8; ++j) ones[j] = (_Float16)1.f;

#define STAGE_KV(tile, nb) do {                                                \
    const _Float16* kn_ = kg + (size_t)(tile) * 64 * DHH;                      \
    const _Float16* vn_ = vg + (tile) * 64;                                    \
    GLD16(kn_ + (size_t)srow * DHH + sc, &Kt[nb][0] + (wv * 64) * 8);          \
    GLD16(vn_ + (size_t)srow * NN + sc, &Vt[nb][0] + (wv * 64) * 8);           \
  } while (0)

  for (int job = 0; job < 2; ++job) {
    const int qb = (job == 0) ? (15 - pair) : pair;
    const int q0 = qb * 128;
    const int base = q0 + wv * 16;
    half8 qf0, qf1;
    {
      const _Float16* qp =
          qh + ((size_t)bh * NN + base + l16) * DHH + quad * 8;
      qf0 = *(const half8*)qp;
      qf1 = *(const half8*)(qp + 32);
    }
    f32x4 o[4] = {};
    f32x4 ls = {};
    const int ktmax = 2 * qb + 1;   // >= 1 always
    STAGE_KV(0, 0);
    STAGE_KV(1, 1);
    int cur = 0;
    for (int kt = 0; kt <= ktmax; ++kt) {
      if (kt + 2 <= ktmax) {
        int nb = cur + 2; if (nb >= 3) nb -= 3;
        STAGE_KV(kt + 2, nb);
        asm volatile("s_waitcnt vmcnt(4)" ::: "memory");  // tile kt landed
      } else if (kt + 1 <= ktmax) {
        asm volatile("s_waitcnt vmcnt(2)" ::: "memory");
      } else {
        asm volatile("s_waitcnt vmcnt(0)" ::: "memory");
      }
      __builtin_amdgcn_s_barrier();
      asm volatile("" ::: "memory");
      if (kt * 64 <= base + 15) {
        half8 kf[4][2], vf[4][2];
        const _Float16* Kb = &Kt[cur][0];
        const _Float16* Vb = &Vt[cur][0];
#pragma unroll
        for (int nt = 0; nt < 4; ++nt) {
          int row = nt * 16 + l16;
          int r7 = row & 7;
          kf[nt][0] = *(const half8*)(Kb + row * 64 + ((quad ^ r7) * 8));
          kf[nt][1] = *(const half8*)(Kb + row * 64 + (((quad + 4) ^ r7) * 8));
          vf[nt][0] = *(const half8*)(Vb + row * 64 + ((quad ^ r7) * 8));
          vf[nt][1] = *(const half8*)(Vb + row * 64 + (((quad + 4) ^ r7) * 8));
        }
        f32x4 s4[4];
#pragma unroll
        for (int nt = 0; nt < 4; ++nt) {
          f32x4 z = {};
          z = __builtin_amdgcn_mfma_f32_16x16x32_f16(qf0, kf[nt][0], z, 0, 0, 0);
          s4[nt] = __builtin_amdgcn_mfma_f32_16x16x32_f16(qf1, kf[nt][1], z, 0, 0, 0);
        }
        if (kt * 64 + 63 > base) {
#pragma unroll
          for (int nt = 0; nt < 4; ++nt) {
            int key = kt * 64 + nt * 16 + l16;
#pragma unroll
            for (int r = 0; r < 4; ++r) {
              float p = (key > base + quad * 4 + r) ? 0.f : __expf(s4[nt][r]);
              Pb[wv][quad * 4 + r][nt * 16 + l16] = (_Float16)p;
            }
          }
        } else {
#pragma unroll
          for (int nt = 0; nt < 4; ++nt)
#pragma unroll
            for (int r = 0; r < 4; ++r)
              Pb[wv][quad * 4 + r][nt * 16 + l16] = (_Float16)__expf(s4[nt][r]);
        }
        asm volatile("s_waitcnt lgkmcnt(0)" ::: "memory");
        half8 pf0 = *(const half8*)&Pb[wv][l16][quad * 8];
        half8 pf1 = *(const half8*)&Pb[wv][l16][32 + quad * 8];
#pragma unroll
        for (int nt = 0; nt < 4; ++nt) {
          o[nt] = __builtin_amdgcn_mfma_f32_16x16x32_f16(pf0, vf[nt][0], o[nt], 0, 0, 0);
          o[nt] = __builtin_amdgcn_mfma_f32_16x16x32_f16(pf1, vf[nt][1], o[nt], 0, 0, 0);
        }
        ls = __builtin_amdgcn_mfma_f32_16x16x32_f16(pf0, ones, ls, 0, 0, 0);
        ls = __builtin_amdgcn_mfma_f32_16x16x32_f16(pf1, ones, ls, 0, 0, 0);
      }
      asm volatile("s_waitcnt lgkmcnt(0)" ::: "memory");
      __builtin_amdgcn_s_barrier();
      asm volatile("" ::: "memory");
      cur = (cur == 2) ? 0 : cur + 1;
    }
#pragma unroll
    for (int r = 0; r < 4; ++r) {
      float inv = 1.f / ls[r];
      int pos = base + quad * 4 + r;
      size_t ob = ((size_t)(b * NN + pos)) * DIMM + h * DHH;
#pragma unroll
      for (int nt = 0; nt < 4; ++nt)
        ah[ob + nt * 16 + l16] = (_Float16)(o[nt][r] * inv);
    }
  }
#undef STAGE_KV
}

// ---------------- out GEMM: 64x64 tile, BK=64, 2-deep (R5 exact) + bias ----------------
__global__ __launch_bounds__(256) void gemm_out_kernel(
    const _Float16* __restrict__ ah, const _Float16* __restrict__ wot,
    const float* __restrict__ bo, float* __restrict__ out) {
  __shared__ __align__(16) char smem[32768];
  _Float16* As = (_Float16*)smem;
  _Float16* Bs = (_Float16*)(smem + 16384);
  const int m0 = blockIdx.x * 64;
  const int n0 = blockIdx.y * 64;
  const int t = threadIdx.x;
  const int wv = t >> 6, lane = t & 63, l16 = lane & 15, quad = lane >> 4;
  const int r  = t >> 3;
  const int cl = t & 7;
  const int csw = (cl ^ (r & 7)) * 8;
  const _Float16* pa0 = ah + (size_t)(m0 + r) * 1024 + csw;
  const _Float16* pa1 = pa0 + 32 * 1024;
  const _Float16* pb0 = wot + (size_t)(n0 + r) * 1024 + csw;
  const _Float16* pb1 = pb0 + 32 * 1024;
  f32x4 acc[4] = {};
  const int arow = wv * 16 + l16;
  const int a7 = arow & 7;
  GLD16(pa0, As + wv * 512);
  GLD16(pa1, As + 2048 + wv * 512);
  GLD16(pb0, Bs + wv * 512);
  GLD16(pb1, Bs + 2048 + wv * 512);
  int cur = 0;
  for (int k0 = 0; k0 < 1024; k0 += 64) {
    if (k0 + 64 < 1024) {
      const int nb = cur ^ 1;
      GLD16(pa0 + k0 + 64, As + nb * 4096 + wv * 512);
      GLD16(pa1 + k0 + 64, As + nb * 4096 + 2048 + wv * 512);
      GLD16(pb0 + k0 + 64, Bs + nb * 4096 + wv * 512);
      GLD16(pb1 + k0 + 64, Bs + nb * 4096 + 2048 + wv * 512);
      asm volatile("s_waitcnt vmcnt(4)" ::: "memory");
    } else {
      asm volatile("s_waitcnt vmcnt(0)" ::: "memory");
    }
    __builtin_amdgcn_s_barrier();
    asm volatile("" ::: "memory");
    const _Float16* Ab = As + cur * 4096;
    const _Float16* Bb = Bs + cur * 4096;
    half8 af0 = *(const half8*)(Ab + arow * 64 + (quad ^ a7) * 8);
    half8 af1 = *(const half8*)(Ab + arow * 64 + ((4 + quad) ^ a7) * 8);
#pragma unroll
    for (int nt = 0; nt < 4; ++nt) {
      int brow = nt * 16 + l16;
      int b7 = brow & 7;
      half8 bf0 = *(const half8*)(Bb + brow * 64 + (quad ^ b7) * 8);
      half8 bf1 = *(const half8*)(Bb + brow * 64 + ((4 + quad) ^ b7) * 8);
      acc[nt] = __builtin_amdgcn_mfma_f32_16x16x32_f16(af0, bf0, acc[nt], 0, 0, 0);
      acc[nt] = __builtin_amdgcn_mfma_f32_16x16x32_f16(af1, bf1, acc[nt], 0, 0, 0);
    }
    asm volatile("s_waitcnt lgkmcnt(0)" ::: "memory");
    __builtin_amdgcn_s_barrier();
    asm volatile("" ::: "memory");
    cur ^= 1;
  }
#pragma unroll
  for (int nt = 0; nt < 4; ++nt) {
    int col = n0 + nt * 16 + l16;
    float bias = bo[col];
#pragma unroll
    for (int rr = 0; rr < 4; ++rr) {
      out[(size_t)(m0 + wv * 16 + quad * 4 + rr) * 1024 + col] = acc[nt][rr] + bias;
    }
  }
}

extern "C" void kernel_launch(void* const* d_in, const int* in_sizes, int n_in,
                              void* d_out, int out_size, void* d_ws, size_t ws_size,
                              hipStream_t stream) {
  (void)in_sizes; (void)n_in; (void)out_size; (void)ws_size;
  const float* x  = (const float*)d_in[0];
  const float* Wq = (const float*)d_in[1];
  const float* Wk = (const float*)d_in[2];
  const float* Wv = (const float*)d_in[3];
  const float* Wo = (const float*)d_in[4];
  const float* bo = (const float*)d_in[5];

  float* out = (float*)d_out;
  float* ko  = out + (size_t)MMR * DIMM;
  float* vo  = ko + (size_t)BB * NHH * NN * DHH;

  char* w = (char*)d_ws;
  _Float16* xh  = (_Float16*)w;                   // 8 MB (dead after gemm_qkv)
  _Float16* ah  = (_Float16*)w;                   // 8 MB (reuses xh region)
  _Float16* wt  = (_Float16*)(w + (8u << 20));    // 8 MB
  _Float16* qh  = (_Float16*)(w + (16u << 20));   // 8 MB (b,h,n,dh) roped, *0.125
  _Float16* kh  = (_Float16*)(w + (24u << 20));   // 8 MB (b,h,n,dh) roped
  _Float16* vth = (_Float16*)(w + (32u << 20));   // 8 MB (b,h,dh,n)

  hipLaunchKernelGGL(cvt_x_kernel, dim3(4096), dim3(256), 0, stream, x, xh);
  hipLaunchKernelGGL(transpose_w_kernel, dim3(16, 16, 4), dim3(256), 0, stream,
                     Wq, Wk, Wv, Wo, wt);
  hipLaunchKernelGGL(gemm_qkv_kernel, dim3(64, 48), dim3(256), 0, stream,
                     xh, wt, ko, vo, qh, kh, vth);
  hipLaunchKernelGGL(fattn_kernel, dim3(256), dim3(512), 0, stream,
                     qh, kh, vth, ah);
  hipLaunchKernelGGL(gemm_out_kernel, dim3(64, 16), dim3(256), 0, stream,
                     ah, wt + (size_t)3 * 1024 * 1024, bo, out);
}

// Round 10
// 197.477 us; speedup vs baseline: 1.1806x; 1.0138x over previous
//
#include <hip/hip_runtime.h>
#include <cstdint>
#include <cmath>

#define BB   2
#define NN   2048
#define DIMM 1024
#define NHH  16
#define DHH  64
#define MMR  (BB * NN)

typedef _Float16 half8  __attribute__((ext_vector_type(8)));
typedef _Float16 half4v __attribute__((ext_vector_type(4)));
typedef float    f32x4  __attribute__((ext_vector_type(4)));

#define GLD16(gp, lp)                                                          \
  __builtin_amdgcn_global_load_lds(                                            \
      (const __attribute__((address_space(1))) unsigned int*)(gp),             \
      (__attribute__((address_space(3))) unsigned int*)(lp), 16, 0, 0)

// ---------------- convert x (fp32 -> f16) ----------------
__global__ __launch_bounds__(256) void cvt_x_kernel(const float* __restrict__ x,
                                                    _Float16* __restrict__ xh) {
  int i = (blockIdx.x * 256 + threadIdx.x) * 4;
  float4 v = *(const float4*)(x + i);
  half4v h;
  h[0] = (_Float16)v.x; h[1] = (_Float16)v.y;
  h[2] = (_Float16)v.z; h[3] = (_Float16)v.w;
  *(half4v*)(xh + i) = h;
}

// ---------------- transpose + convert weights: W[k][n] -> Wt[n][k] f16 ----------------
__global__ __launch_bounds__(256) void transpose_w_kernel(
    const float* __restrict__ Wq, const float* __restrict__ Wk,
    const float* __restrict__ Wv, const float* __restrict__ Wo,
    _Float16* __restrict__ wt) {
  __shared__ float tile[64][65];
  int z = blockIdx.z;
  const float* W = (z == 0) ? Wq : (z == 1) ? Wk : (z == 2) ? Wv : Wo;
  _Float16* dst = wt + (size_t)z * 1024 * 1024;
  int r0 = blockIdx.x * 64;
  int c0 = blockIdx.y * 64;
  int t = threadIdx.x;
  int tr = t >> 4;
  int tc = (t & 15) * 4;
#pragma unroll
  for (int i = 0; i < 4; ++i) {
    float4 v = *(const float4*)(W + (size_t)(r0 + tr + i * 16) * 1024 + c0 + tc);
    tile[tr + i * 16][tc + 0] = v.x;
    tile[tr + i * 16][tc + 1] = v.y;
    tile[tr + i * 16][tc + 2] = v.z;
    tile[tr + i * 16][tc + 3] = v.w;
  }
  __syncthreads();
#pragma unroll
  for (int i = 0; i < 4; ++i) {
    int nl = tr + i * 16;
    half4v hv;
    hv[0] = (_Float16)tile[tc + 0][nl];
    hv[1] = (_Float16)tile[tc + 1][nl];
    hv[2] = (_Float16)tile[tc + 2][nl];
    hv[3] = (_Float16)tile[tc + 3][nl];
    *(half4v*)(dst + (size_t)(c0 + nl) * 1024 + r0 + tc) = hv;
  }
}

// ---------------- QKV GEMM: 64x64 tile, BK=64, dbuf, 2x2 wave layout ----------------
// R9 diagnosis: with 3 resident blocks the CU moves 3x(16KB write + 40KB read)
// = 168KB LDS per ~700cy iter = 240 B/cy ~ the 256 B/clock LDS ceiling ->
// CU-aggregate LDS-bandwidth-bound. Fix: wave-tile 16x64 -> 32x32 (2x2 waves):
// block fragment reads 40KB -> 32KB per iter (read cost 1/16+1/64 -> 2/32 per
// elem), same 8 MFMA + 8 ds_read_b128 per wave, same grid 3072 / 32KB LDS /
// staging / barrier discipline (do NOT reduce grid -- R6/R8 evidence).
__global__ __launch_bounds__(256) void gemm_qkv_kernel(
    const _Float16* __restrict__ xh, const _Float16* __restrict__ wt,
    float* __restrict__ ko, float* __restrict__ vo,
    _Float16* __restrict__ qh, _Float16* __restrict__ kh,
    _Float16* __restrict__ vth) {
  __shared__ __align__(16) char smem[32768];
  _Float16* As = (_Float16*)smem;            // [2][64][64] halfs, 16KB
  _Float16* Bs = (_Float16*)(smem + 16384);  // [2][64][64] halfs, 16KB
  float (*Cs)[65] = (float(*)[65])smem;      // 64x65 f32 epilogue reuse (16.6KB)

  const int m0  = blockIdx.x * 64;
  const int ngl = blockIdx.y * 64;
  const int mat = ngl >> 10;
  const int n0  = ngl & 1023;
  const _Float16* wb = wt + (size_t)mat * 1024 * 1024;
  const int t = threadIdx.x;
  const int wv = t >> 6, lane = t & 63, l16 = lane & 15, quad = lane >> 4;
  const int wr = wv >> 1, wc = wv & 1;
  const int r  = t >> 3;       // 0..31
  const int cl = t & 7;
  const int csw = (cl ^ (r & 7)) * 8;   // (r+32)&7 == r&7
  const _Float16* pa0 = xh + (size_t)(m0 + r) * 1024 + csw;
  const _Float16* pa1 = pa0 + 32 * 1024;
  const _Float16* pb0 = wb + (size_t)(n0 + r) * 1024 + csw;
  const _Float16* pb1 = pb0 + 32 * 1024;
  f32x4 acc[2][2] = {};
  GLD16(pa0, As + wv * 512);
  GLD16(pa1, As + 2048 + wv * 512);
  GLD16(pb0, Bs + wv * 512);
  GLD16(pb1, Bs + 2048 + wv * 512);
  int cur = 0;
  for (int k0 = 0; k0 < 1024; k0 += 64) {
    if (k0 + 64 < 1024) {
      const int nb = cur ^ 1;
      GLD16(pa0 + k0 + 64, As + nb * 4096 + wv * 512);
      GLD16(pa1 + k0 + 64, As + nb * 4096 + 2048 + wv * 512);
      GLD16(pb0 + k0 + 64, Bs + nb * 4096 + wv * 512);
      GLD16(pb1 + k0 + 64, Bs + nb * 4096 + 2048 + wv * 512);
      asm volatile("s_waitcnt vmcnt(4)" ::: "memory");
    } else {
      asm volatile("s_waitcnt vmcnt(0)" ::: "memory");
    }
    __builtin_amdgcn_s_barrier();
    asm volatile("" ::: "memory");
    const _Float16* Ab = As + cur * 4096;
    const _Float16* Bb = Bs + cur * 4096;
    half8 af[2][2], bf[2][2];
#pragma unroll
    for (int mi = 0; mi < 2; ++mi) {
      int ar = wr * 32 + mi * 16 + l16;
      int a7 = ar & 7;
      af[mi][0] = *(const half8*)(Ab + ar * 64 + ((quad ^ a7) * 8));
      af[mi][1] = *(const half8*)(Ab + ar * 64 + (((4 + quad) ^ a7) * 8));
    }
#pragma unroll
    for (int nt = 0; nt < 2; ++nt) {
      int br = wc * 32 + nt * 16 + l16;
      int b7 = br & 7;
      bf[nt][0] = *(const half8*)(Bb + br * 64 + ((quad ^ b7) * 8));
      bf[nt][1] = *(const half8*)(Bb + br * 64 + (((4 + quad) ^ b7) * 8));
    }
#pragma unroll
    for (int mi = 0; mi < 2; ++mi)
#pragma unroll
      for (int nt = 0; nt < 2; ++nt) {
        acc[mi][nt] = __builtin_amdgcn_mfma_f32_16x16x32_f16(af[mi][0], bf[nt][0], acc[mi][nt], 0, 0, 0);
        acc[mi][nt] = __builtin_amdgcn_mfma_f32_16x16x32_f16(af[mi][1], bf[nt][1], acc[mi][nt], 0, 0, 0);
      }
    // reads of buf[cur] must RETIRE before crossing: next iter's prefetch
    // overwrites this buffer (raw s_barrier does not drain lgkm).
    asm volatile("s_waitcnt lgkmcnt(0)" ::: "memory");
    __builtin_amdgcn_s_barrier();
    asm volatile("" ::: "memory");
    cur ^= 1;
  }
  // ---------- epilogue: RoPE/scatter through Cs ----------
#pragma unroll
  for (int mi = 0; mi < 2; ++mi)
#pragma unroll
    for (int nt = 0; nt < 2; ++nt)
#pragma unroll
      for (int rr = 0; rr < 4; ++rr)
        Cs[wr * 32 + mi * 16 + quad * 4 + rr][wc * 32 + nt * 16 + l16] = acc[mi][nt][rr];
  __syncthreads();
  int lr = t >> 2;
  int cseg = (t & 3) * 16;
  int m = m0 + lr;
  int b = m >> 11;
  int pos = m & 2047;
  int h = n0 >> 6;
  int bhh = b * NHH + h;
  float vals[16];
  if (mat == 2) {
#pragma unroll
    for (int j = 0; j < 16; ++j) vals[j] = Cs[lr][cseg + j];
  } else {
    float fpos = (float)pos;
#pragma unroll
    for (int j = 0; j < 16; ++j) {
      int i = cseg + j;
      int jd = (i < 32) ? i : (i - 32);
      float invf = exp2f((float)jd * -0.41524101186092029f);
      float ang = fpos * invf;
      float sv, cv;
      sincosf(ang, &sv, &cv);
      float partner = (i < 32) ? -Cs[lr][2 * i + 1] : Cs[lr][2 * (i - 32)];
      vals[j] = Cs[lr][i] * cv + partner * sv;
    }
  }
  size_t rowb = ((size_t)bhh * NN + pos) * DHH + cseg;
  if (mat == 0) {
    half8 h0, h1;
#pragma unroll
    for (int j = 0; j < 8; ++j) { h0[j] = (_Float16)(vals[j] * 0.125f); h1[j] = (_Float16)(vals[8 + j] * 0.125f); }
    *(half8*)(qh + rowb) = h0;
    *(half8*)(qh + rowb + 8) = h1;
  } else if (mat == 1) {
#pragma unroll
    for (int j4 = 0; j4 < 4; ++j4) {
      float4 o;
      o.x = vals[j4 * 4 + 0]; o.y = vals[j4 * 4 + 1];
      o.z = vals[j4 * 4 + 2]; o.w = vals[j4 * 4 + 3];
      *(float4*)(ko + rowb + j4 * 4) = o;
    }
    half8 h0, h1;
#pragma unroll
    for (int j = 0; j < 8; ++j) { h0[j] = (_Float16)vals[j]; h1[j] = (_Float16)vals[8 + j]; }
    *(half8*)(kh + rowb) = h0;
    *(half8*)(kh + rowb + 8) = h1;
  } else {
#pragma unroll
    for (int j4 = 0; j4 < 4; ++j4) {
      float4 o;
      o.x = vals[j4 * 4 + 0]; o.y = vals[j4 * 4 + 1];
      o.z = vals[j4 * 4 + 2]; o.w = vals[j4 * 4 + 3];
      *(float4*)(vo + rowb + j4 * 4) = o;
    }
#pragma unroll
    for (int j = 0; j < 16; ++j)
      vth[((size_t)bhh * DHH + cseg + j) * NN + pos] = (_Float16)vals[j];
  }
}

// ---------------- MFMA flash attention v6 (causal), f16 ----------------
// 8 waves x 512 threads; uniform pair-blocks; XCD-chunked bh; 3-deep K/V
// pipeline with counted vmcnt. (R7-measured: ~20us faster than v5.)
__global__ __launch_bounds__(512) void fattn_kernel(
    const _Float16* __restrict__ qh, const _Float16* __restrict__ kh,
    const _Float16* __restrict__ vth, _Float16* __restrict__ ah) {
  __shared__ __align__(16) _Float16 Kt[3][4096];
  __shared__ __align__(16) _Float16 Vt[3][4096];
  __shared__ __align__(16) _Float16 Pb[8][16][72];
  const int lin  = (int)blockIdx.x;          // 0..255
  const int xcd  = lin & 7;
  const int slot = lin >> 3;                 // 0..31 within XCD
  const int bh   = xcd * 4 + (slot & 3);     // 4 bh per XCD
  const int pair = slot >> 2;                // 0..7
  const int t = threadIdx.x;
  const int wv = t >> 6, lane = t & 63, l16 = lane & 15, quad = lane >> 4;
  const int b = bh >> 4, h = bh & 15;
  const _Float16* kg = kh + (size_t)bh * NN * DHH;
  const _Float16* vg = vth + (size_t)bh * DHH * NN;
  const int srow = t >> 3;
  const int sc   = ((t & 7) ^ (srow & 7)) * 8;
  half8 ones;
#pragma unroll
  for (int j = 0; j < 8; ++j) ones[j] = (_Float16)1.f;

#define STAGE_KV(tile, nb) do {                                                \
    const _Float16* kn_ = kg + (size_t)(tile) * 64 * DHH;                      \
    const _Float16* vn_ = vg + (tile) * 64;                                    \
    GLD16(kn_ + (size_t)srow * DHH + sc, &Kt[nb][0] + (wv * 64) * 8);          \
    GLD16(vn_ + (size_t)srow * NN + sc, &Vt[nb][0] + (wv * 64) * 8);           \
  } while (0)

  for (int job = 0; job < 2; ++job) {
    const int qb = (job == 0) ? (15 - pair) : pair;
    const int q0 = qb * 128;
    const int base = q0 + wv * 16;
    half8 qf0, qf1;
    {
      const _Float16* qp =
          qh + ((size_t)bh * NN + base + l16) * DHH + quad * 8;
      qf0 = *(const half8*)qp;
      qf1 = *(const half8*)(qp + 32);
    }
    f32x4 o[4] = {};
    f32x4 ls = {};
    const int ktmax = 2 * qb + 1;   // >= 1 always
    STAGE_KV(0, 0);
    STAGE_KV(1, 1);
    int cur = 0;
    for (int kt = 0; kt <= ktmax; ++kt) {
      if (kt + 2 <= ktmax) {
        int nb = cur + 2; if (nb >= 3) nb -= 3;
        STAGE_KV(kt + 2, nb);
        asm volatile("s_waitcnt vmcnt(4)" ::: "memory");  // tile kt landed
      } else if (kt + 1 <= ktmax) {
        asm volatile("s_waitcnt vmcnt(2)" ::: "memory");
      } else {
        asm volatile("s_waitcnt vmcnt(0)" ::: "memory");
      }
      __builtin_amdgcn_s_barrier();
      asm volatile("" ::: "memory");
      if (kt * 64 <= base + 15) {
        half8 kf[4][2], vf[4][2];
        const _Float16* Kb = &Kt[cur][0];
        const _Float16* Vb = &Vt[cur][0];
#pragma unroll
        for (int nt = 0; nt < 4; ++nt) {
          int row = nt * 16 + l16;
          int r7 = row & 7;
          kf[nt][0] = *(const half8*)(Kb + row * 64 + ((quad ^ r7) * 8));
          kf[nt][1] = *(const half8*)(Kb + row * 64 + (((quad + 4) ^ r7) * 8));
          vf[nt][0] = *(const half8*)(Vb + row * 64 + ((quad ^ r7) * 8));
          vf[nt][1] = *(const half8*)(Vb + row * 64 + (((quad + 4) ^ r7) * 8));
        }
        f32x4 s4[4];
#pragma unroll
        for (int nt = 0; nt < 4; ++nt) {
          f32x4 z = {};
          z = __builtin_amdgcn_mfma_f32_16x16x32_f16(qf0, kf[nt][0], z, 0, 0, 0);
          s4[nt] = __builtin_amdgcn_mfma_f32_16x16x32_f16(qf1, kf[nt][1], z, 0, 0, 0);
        }
        if (kt * 64 + 63 > base) {
#pragma unroll
          for (int nt = 0; nt < 4; ++nt) {
            int key = kt * 64 + nt * 16 + l16;
#pragma unroll
            for (int r = 0; r < 4; ++r) {
              float p = (key > base + quad * 4 + r) ? 0.f : __expf(s4[nt][r]);
              Pb[wv][quad * 4 + r][nt * 16 + l16] = (_Float16)p;
            }
          }
        } else {
#pragma unroll
          for (int nt = 0; nt < 4; ++nt)
#pragma unroll
            for (int r = 0; r < 4; ++r)
              Pb[wv][quad * 4 + r][nt * 16 + l16] = (_Float16)__expf(s4[nt][r]);
        }
        asm volatile("s_waitcnt lgkmcnt(0)" ::: "memory");
        half8 pf0 = *(const half8*)&Pb[wv][l16][quad * 8];
        half8 pf1 = *(const half8*)&Pb[wv][l16][32 + quad * 8];
#pragma unroll
        for (int nt = 0; nt < 4; ++nt) {
          o[nt] = __builtin_amdgcn_mfma_f32_16x16x32_f16(pf0, vf[nt][0], o[nt], 0, 0, 0);
          o[nt] = __builtin_amdgcn_mfma_f32_16x16x32_f16(pf1, vf[nt][1], o[nt], 0, 0, 0);
        }
        ls = __builtin_amdgcn_mfma_f32_16x16x32_f16(pf0, ones, ls, 0, 0, 0);
        ls = __builtin_amdgcn_mfma_f32_16x16x32_f16(pf1, ones, ls, 0, 0, 0);
      }
      asm volatile("s_waitcnt lgkmcnt(0)" ::: "memory");
      __builtin_amdgcn_s_barrier();
      asm volatile("" ::: "memory");
      cur = (cur == 2) ? 0 : cur + 1;
    }
#pragma unroll
    for (int r = 0; r < 4; ++r) {
      float inv = 1.f / ls[r];
      int pos = base + quad * 4 + r;
      size_t ob = ((size_t)(b * NN + pos)) * DIMM + h * DHH;
#pragma unroll
      for (int nt = 0; nt < 4; ++nt)
        ah[ob + nt * 16 + l16] = (_Float16)(o[nt][r] * inv);
    }
  }
#undef STAGE_KV
}

// ---------------- out GEMM: 64x64 tile, BK=64, dbuf, 2x2 wave layout + bias ----------------
__global__ __launch_bounds__(256) void gemm_out_kernel(
    const _Float16* __restrict__ ah, const _Float16* __restrict__ wot,
    const float* __restrict__ bo, float* __restrict__ out) {
  __shared__ __align__(16) char smem[32768];
  _Float16* As = (_Float16*)smem;
  _Float16* Bs = (_Float16*)(smem + 16384);
  const int m0 = blockIdx.x * 64;
  const int n0 = blockIdx.y * 64;
  const int t = threadIdx.x;
  const int wv = t >> 6, lane = t & 63, l16 = lane & 15, quad = lane >> 4;
  const int wr = wv >> 1, wc = wv & 1;
  const int r  = t >> 3;
  const int cl = t & 7;
  const int csw = (cl ^ (r & 7)) * 8;
  const _Float16* pa0 = ah + (size_t)(m0 + r) * 1024 + csw;
  const _Float16* pa1 = pa0 + 32 * 1024;
  const _Float16* pb0 = wot + (size_t)(n0 + r) * 1024 + csw;
  const _Float16* pb1 = pb0 + 32 * 1024;
  f32x4 acc[2][2] = {};
  GLD16(pa0, As + wv * 512);
  GLD16(pa1, As + 2048 + wv * 512);
  GLD16(pb0, Bs + wv * 512);
  GLD16(pb1, Bs + 2048 + wv * 512);
  int cur = 0;
  for (int k0 = 0; k0 < 1024; k0 += 64) {
    if (k0 + 64 < 1024) {
      const int nb = cur ^ 1;
      GLD16(pa0 + k0 + 64, As + nb * 4096 + wv * 512);
      GLD16(pa1 + k0 + 64, As + nb * 4096 + 2048 + wv * 512);
      GLD16(pb0 + k0 + 64, Bs + nb * 4096 + wv * 512);
      GLD16(pb1 + k0 + 64, Bs + nb * 4096 + 2048 + wv * 512);
      asm volatile("s_waitcnt vmcnt(4)" ::: "memory");
    } else {
      asm volatile("s_waitcnt vmcnt(0)" ::: "memory");
    }
    __builtin_amdgcn_s_barrier();
    asm volatile("" ::: "memory");
    const _Float16* Ab = As + cur * 4096;
    const _Float16* Bb = Bs + cur * 4096;
    half8 af[2][2], bf[2][2];
#pragma unroll
    for (int mi = 0; mi < 2; ++mi) {
      int ar = wr * 32 + mi * 16 + l16;
      int a7 = ar & 7;
      af[mi][0] = *(const half8*)(Ab + ar * 64 + ((quad ^ a7) * 8));
      af[mi][1] = *(const half8*)(Ab + ar * 64 + (((4 + quad) ^ a7) * 8));
    }
#pragma unroll
    for (int nt = 0; nt < 2; ++nt) {
      int br = wc * 32 + nt * 16 + l16;
      int b7 = br & 7;
      bf[nt][0] = *(const half8*)(Bb + br * 64 + ((quad ^ b7) * 8));
      bf[nt][1] = *(const half8*)(Bb + br * 64 + (((4 + quad) ^ b7) * 8));
    }
#pragma unroll
    for (int mi = 0; mi < 2; ++mi)
#pragma unroll
      for (int nt = 0; nt < 2; ++nt) {
        acc[mi][nt] = __builtin_amdgcn_mfma_f32_16x16x32_f16(af[mi][0], bf[nt][0], acc[mi][nt], 0, 0, 0);
        acc[mi][nt] = __builtin_amdgcn_mfma_f32_16x16x32_f16(af[mi][1], bf[nt][1], acc[mi][nt], 0, 0, 0);
      }
    asm volatile("s_waitcnt lgkmcnt(0)" ::: "memory");
    __builtin_amdgcn_s_barrier();
    asm volatile("" ::: "memory");
    cur ^= 1;
  }
#pragma unroll
  for (int mi = 0; mi < 2; ++mi)
#pragma unroll
    for (int nt = 0; nt < 2; ++nt) {
      int col = n0 + wc * 32 + nt * 16 + l16;
      float bias = bo[col];
#pragma unroll
      for (int rr = 0; rr < 4; ++rr) {
        out[(size_t)(m0 + wr * 32 + mi * 16 + quad * 4 + rr) * 1024 + col] =
            acc[mi][nt][rr] + bias;
      }
    }
}

extern "C" void kernel_launch(void* const* d_in, const int* in_sizes, int n_in,
                              void* d_out, int out_size, void* d_ws, size_t ws_size,
                              hipStream_t stream) {
  (void)in_sizes; (void)n_in; (void)out_size; (void)ws_size;
  const float* x  = (const float*)d_in[0];
  const float* Wq = (const float*)d_in[1];
  const float* Wk = (const float*)d_in[2];
  const float* Wv = (const float*)d_in[3];
  const float* Wo = (const float*)d_in[4];
  const float* bo = (const float*)d_in[5];

  float* out = (float*)d_out;
  float* ko  = out + (size_t)MMR * DIMM;
  float* vo  = ko + (size_t)BB * NHH * NN * DHH;

  char* w = (char*)d_ws;
  _Float16* xh  = (_Float16*)w;                   // 8 MB (dead after gemm_qkv)
  _Float16* ah  = (_Float16*)w;                   // 8 MB (reuses xh region)
  _Float16* wt  = (_Float16*)(w + (8u << 20));    // 8 MB
  _Float16* qh  = (_Float16*)(w + (16u << 20));   // 8 MB (b,h,n,dh) roped, *0.125
  _Float16* kh  = (_Float16*)(w + (24u << 20));   // 8 MB (b,h,n,dh) roped
  _Float16* vth = (_Float16*)(w + (32u << 20));   // 8 MB (b,h,dh,n)

  hipLaunchKernelGGL(cvt_x_kernel, dim3(4096), dim3(256), 0, stream, x, xh);
  hipLaunchKernelGGL(transpose_w_kernel, dim3(16, 16, 4), dim3(256), 0, stream,
                     Wq, Wk, Wv, Wo, wt);
  hipLaunchKernelGGL(gemm_qkv_kernel, dim3(64, 48), dim3(256), 0, stream,
                     xh, wt, ko, vo, qh, kh, vth);
  hipLaunchKernelGGL(fattn_kernel, dim3(256), dim3(512), 0, stream,
                     qh, kh, vth, ah);
  hipLaunchKernelGGL(gemm_out_kernel, dim3(64, 16), dim3(256), 0, stream,
                     ah, wt + (size_t)3 * 1024 * 1024, bo, out);
}